// Round 5
// baseline (334.543 us; speedup 1.0000x reference)
//
#include <hip/hip_runtime.h>
#include <hip/hip_bf16.h>

// BatchedSemiAttention: B=2, N=50000, E=800000, INP=128, KEY=64, VAL=128
#define NB    2
#define NNODE 50000
#define NEDGE 800000
#define INPD  128
#define KEYD  64
#define VALD  128
#define MTOT  (NB * NNODE)   // 100000 flattened (b,n) rows
#define VBLK  3125           // NNODE/16 blocks for the values GEMM part
#define CHUNK 512
#define NCHUNK ((NNODE + CHUNK - 1) / CHUNK)   // 98
#define EPB   ((NEDGE + NCHUNK - 1) / NCHUNK)  // edges per scan_scatter block

typedef __attribute__((ext_vector_type(8))) short bf16x8;
typedef __attribute__((ext_vector_type(4))) float f32x4;

__device__ __forceinline__ unsigned short f2bf(float f) {
    unsigned u = __float_as_uint(f);
    u += 0x7FFFu + ((u >> 16) & 1u);   // RNE
    return (unsigned short)(u >> 16);
}

// ---------------------------------------------------------------------------
// Prep: bf16 transposes of v_w / out_w into [n][k]; kwsum (col-sums of k_w,
// +kb sum at [128]); zero CSR counts + sync flags. One launch.
// ---------------------------------------------------------------------------
__global__ void prep_kernel(const float* __restrict__ kw, const float* __restrict__ kb,
                            const float* __restrict__ vw, const float* __restrict__ ow,
                            float* __restrict__ kwsum,
                            unsigned short* __restrict__ vwT, unsigned short* __restrict__ owT,
                            int* __restrict__ counts, int* __restrict__ flags) {
    int bid = blockIdx.x, tid = threadIdx.x;
    if (bid < 64) {
        int idx = bid * 256 + tid;            // [0,16384)
        int n = idx >> 7, k = idx & 127;
        vwT[idx] = f2bf(vw[k * VALD + n]);
    } else if (bid < 128) {
        int idx = (bid - 64) * 256 + tid;
        int n = idx >> 7, k = idx & 127;
        owT[idx] = f2bf(ow[k * VALD + n]);
    } else if (bid == 128) {
        if (tid < INPD) {
            float s = 0.f;
            for (int j = 0; j < KEYD; ++j) s += kw[tid * KEYD + j];
            kwsum[tid] = s;
        }
        if (tid == 129) {
            float s = 0.f;
            for (int j = 0; j < KEYD; ++j) s += kb[j];
            kwsum[INPD] = s;                  // kbsum
        }
        if (tid == 200) flags[0] = 0;
        if (tid == 201) flags[1] = 0;
    } else {
        int idx = (bid - 129) * 256 + tid;
        if (idx < NNODE) counts[idx] = 0;
    }
}

// ---------------------------------------------------------------------------
// Fused values GEMM (both batches, 16 nodes/block) + ksum + edge histogram.
//   xs   [32][132] fp32 - x tile (rows 0-15 = batch0, 16-31 = batch1)
//   pk32 [16][132] u32  - packed (b0|b1<<16) output tile; conflict-free b32
//                         writes (bank = 4*nl + col), repacked on flush.
// values_pk layout per node: 64 x uint2 { b0 cols(2l,2l+1), b1 cols(2l,2l+1) }
// -> one dwordx2 per edge in the aggregate phase.
// ---------------------------------------------------------------------------
__global__ __launch_bounds__(512)
void values_build_kernel(const float* __restrict__ x, const float* __restrict__ vb,
                         const float* __restrict__ kwsum,
                         const unsigned short* __restrict__ vwT,
                         const int* __restrict__ rows_e,
                         uint2* __restrict__ values_pk, float* __restrict__ ksum,
                         int* __restrict__ counts) {
    __shared__ float xs[32 * 132];            // 16896 B
    __shared__ unsigned pk32[16 * 132];       // 8448 B
    if (blockIdx.x >= VBLK) {
        // histogram part, overlapped with the GEMM blocks
        int e = (blockIdx.x - VBLK) * 512 + threadIdx.x;
        if (e < NEDGE) atomicAdd(&counts[rows_e[e]], 1);
        return;
    }
    int node0 = blockIdx.x * 16;
    int tid = threadIdx.x;
    // Coalesced x-tile load: one float4 per thread per batch (2 x 8 KB contiguous).
    {
        float4 v0 = ((const float4*)(x + (size_t)node0 * INPD))[tid];
        float4 v1 = ((const float4*)(x + (size_t)(NNODE + node0) * INPD))[tid];
        int row = tid >> 5;           // 0..15
        int col = (tid & 31) * 4;     // 0..124
        *(float4*)(xs + row * 132 + col) = v0;
        *(float4*)(xs + (16 + row) * 132 + col) = v1;
    }
    __syncthreads();

    int wave = tid >> 6, lane = tid & 63;
    int m = lane & 15, quad = lane >> 4;
    int n0 = wave * 16;
    f32x4 acc0 = {0.f, 0.f, 0.f, 0.f};   // batch 0
    f32x4 acc1 = {0.f, 0.f, 0.f, 0.f};   // batch 1
    float kpart = 0.f;
    const float* r0 = xs + m * 132;
    const float* r1 = xs + (16 + m) * 132;
#pragma unroll
    for (int kk = 0; kk < 4; ++kk) {
        int k0 = kk * 32 + quad * 8;
        float4 a0 = *(const float4*)(r0 + k0);
        float4 a1 = *(const float4*)(r0 + k0 + 4);
        float4 c0 = *(const float4*)(r1 + k0);
        float4 c1 = *(const float4*)(r1 + k0 + 4);
        bf16x8 bfrag = *(const bf16x8*)(vwT + (size_t)(n0 + m) * INPD + k0);
        union { bf16x8 v; unsigned short h[8]; } ua;
        ua.h[0] = f2bf(a0.x); ua.h[1] = f2bf(a0.y); ua.h[2] = f2bf(a0.z); ua.h[3] = f2bf(a0.w);
        ua.h[4] = f2bf(a1.x); ua.h[5] = f2bf(a1.y); ua.h[6] = f2bf(a1.z); ua.h[7] = f2bf(a1.w);
        acc0 = __builtin_amdgcn_mfma_f32_16x16x32_bf16(ua.v, bfrag, acc0, 0, 0, 0);
        union { bf16x8 v; unsigned short h[8]; } ub;
        ub.h[0] = f2bf(c0.x); ub.h[1] = f2bf(c0.y); ub.h[2] = f2bf(c0.z); ub.h[3] = f2bf(c0.w);
        ub.h[4] = f2bf(c1.x); ub.h[5] = f2bf(c1.y); ub.h[6] = f2bf(c1.z); ub.h[7] = f2bf(c1.w);
        acc1 = __builtin_amdgcn_mfma_f32_16x16x32_bf16(ub.v, bfrag, acc1, 0, 0, 0);
        if (wave == 0) {
            float4 ka = *(const float4*)(kwsum + k0);
            float4 kc = *(const float4*)(kwsum + k0 + 4);
            kpart += a0.x * ka.x + a0.y * ka.y + a0.z * ka.z + a0.w * ka.w
                   + a1.x * kc.x + a1.y * kc.y + a1.z * kc.z + a1.w * kc.w;
        } else if (wave == 1) {
            float4 ka = *(const float4*)(kwsum + k0);
            float4 kc = *(const float4*)(kwsum + k0 + 4);
            kpart += c0.x * ka.x + c0.y * ka.y + c0.z * ka.z + c0.w * ka.w
                   + c1.x * kc.x + c1.y * kc.y + c1.z * kc.z + c1.w * kc.w;
        }
    }
    int col = n0 + m;
    float vbc = vb[col];
#pragma unroll
    for (int r = 0; r < 4; ++r) {
        int nl = quad * 4 + r;                  // node_local
        pk32[nl * 132 + col] = (unsigned)f2bf(acc0[r] + vbc)
                             | ((unsigned)f2bf(acc1[r] + vbc) << 16);
    }
    if (wave < 2) {
        kpart += __shfl_xor(kpart, 16);
        kpart += __shfl_xor(kpart, 32);
        if (quad == 0) ksum[(wave == 0 ? 0 : NNODE) + node0 + m] = kpart + kwsum[INPD];
    }
    __syncthreads();
    // Repack + coalesced flush: thread t -> node t>>5, col-group t&31 (4 cols).
    {
        int nl = tid >> 5, cg = tid & 31;
        const unsigned* p = pk32 + nl * 132 + cg * 4;
        unsigned p0 = p[0], p1 = p[1], p2 = p[2], p3 = p[3];
        uint4 r;
        r.x = (p0 & 0xFFFFu) | (p1 << 16);                 // b0 cols 4cg,4cg+1
        r.y = (p0 >> 16) | (p1 & 0xFFFF0000u);             // b1 cols 4cg,4cg+1
        r.z = (p2 & 0xFFFFu) | (p3 << 16);                 // b0 cols 4cg+2,4cg+3
        r.w = (p2 >> 16) | (p3 & 0xFFFF0000u);             // b1 cols 4cg+2,4cg+3
        *(uint4*)((char*)values_pk + (size_t)(node0 + nl) * 512 + cg * 16) = r;
    }
}

// ---------------------------------------------------------------------------
// Fused scan1+scan2+scan3+scatter: 98 blocks (always co-resident on 256 CUs),
// device-scope atomics for the two global barriers (G16: no plain-load
// cross-XCD communication).
// ---------------------------------------------------------------------------
__global__ __launch_bounds__(256)
void scan_scatter_kernel(const int* __restrict__ counts,
                         int* __restrict__ psum, int* __restrict__ flags,
                         int* __restrict__ offsets, int* __restrict__ cursor,
                         const int* __restrict__ rows, const int* __restrict__ cols,
                         const float* __restrict__ conn,
                         uint2* __restrict__ edge_s) {
    __shared__ int wt0[4], wt1[4];
    __shared__ int pshared[128];
    __shared__ int base_sh;
    int b = blockIdx.x, t = threadIdx.x;
    int lane = t & 63, wv = t >> 6;
    int i0 = b * CHUNK + t, i1 = i0 + 256;
    int v0 = (i0 < NNODE) ? counts[i0] : 0;
    int v1 = (i1 < NNODE) ? counts[i1] : 0;
    // ---- phase 1: publish this chunk's sum
    {
        int v = v0 + v1;
#pragma unroll
        for (int o = 1; o < 64; o <<= 1) v += __shfl_xor(v, o);
        if (lane == 0) wt0[wv] = v;
        __syncthreads();
        if (t == 0) {
            int s = wt0[0] + wt0[1] + wt0[2] + wt0[3];
            __hip_atomic_store(&psum[b], s, __ATOMIC_RELEASE, __HIP_MEMORY_SCOPE_AGENT);
            __hip_atomic_fetch_add(&flags[0], 1, __ATOMIC_ACQ_REL, __HIP_MEMORY_SCOPE_AGENT);
            while (__hip_atomic_load(&flags[0], __ATOMIC_ACQUIRE, __HIP_MEMORY_SCOPE_AGENT) < NCHUNK) {}
        }
        __syncthreads();
    }
    // ---- phase 2: chunk base + within-chunk exclusive scan -> offsets/cursor
    if (t < 128)
        pshared[t] = (t < NCHUNK)
            ? __hip_atomic_load(&psum[t], __ATOMIC_RELAXED, __HIP_MEMORY_SCOPE_AGENT) : 0;
    __syncthreads();
    if (t == 0) {
        int s = 0;
        for (int j = 0; j < b; ++j) s += pshared[j];
        base_sh = s;
        if (b == 0) {
            int tot = 0;
            for (int j = 0; j < NCHUNK; ++j) tot += pshared[j];
            offsets[NNODE] = tot;
        }
    }
    __syncthreads();
    {
        int x0 = v0, x1 = v1;
#pragma unroll
        for (int o = 1; o < 64; o <<= 1) { int y = __shfl_up(x0, o); if (lane >= o) x0 += y; }
#pragma unroll
        for (int o = 1; o < 64; o <<= 1) { int y = __shfl_up(x1, o); if (lane >= o) x1 += y; }
        if (lane == 63) { wt0[wv] = x0; wt1[wv] = x1; }
        __syncthreads();
        int base = base_sh;
        int acc0 = base;
        for (int j = 0; j < wv; ++j) acc0 += wt0[j];
        int excl0 = acc0 + x0 - v0;
        int acc1 = base + wt0[0] + wt0[1] + wt0[2] + wt0[3];
        for (int j = 0; j < wv; ++j) acc1 += wt1[j];
        int excl1 = acc1 + x1 - v1;
        if (i0 < NNODE) {
            offsets[i0] = excl0;
            __hip_atomic_store(&cursor[i0], excl0, __ATOMIC_RELAXED, __HIP_MEMORY_SCOPE_AGENT);
        }
        if (i1 < NNODE) {
            offsets[i1] = excl1;
            __hip_atomic_store(&cursor[i1], excl1, __ATOMIC_RELAXED, __HIP_MEMORY_SCOPE_AGENT);
        }
    }
    // ---- barrier 2: all cursors ready
    __syncthreads();
    if (t == 0) {
        __hip_atomic_fetch_add(&flags[1], 1, __ATOMIC_ACQ_REL, __HIP_MEMORY_SCOPE_AGENT);
        while (__hip_atomic_load(&flags[1], __ATOMIC_ACQUIRE, __HIP_MEMORY_SCOPE_AGENT) < NCHUNK) {}
    }
    __syncthreads();
    // ---- phase 3: scatter this block's edge slice
    int e0 = b * EPB;
    int e1 = min(e0 + EPB, NEDGE);
    for (int e = e0 + t; e < e1; e += 256) {
        int r = rows[e];
        int o = atomicAdd(&cursor[r], 1);
        edge_s[o] = make_uint2((unsigned)cols[e], __float_as_uint(conn[e]));
    }
}

// ---------------------------------------------------------------------------
// Fused aggregate + output GEMM + silu + LayerNorm. Block owns 16 consecutive
// nodes: aggregate phase (wave w -> nodes i0+4w..+3, softmax + gather) writes
// bf16-packed agg rows to LDS; out phase runs the 2 out-tiles (batch0/batch1)
// entirely from LDS. agg never touches global memory.
// ---------------------------------------------------------------------------
__global__ __launch_bounds__(256)
void agg_out_kernel(const int* __restrict__ offsets,
                    const uint2* __restrict__ edge_s,
                    const float* __restrict__ ksum,
                    const uint2* __restrict__ values_pk,
                    const unsigned short* __restrict__ owT,
                    const float* __restrict__ ob,
                    const float* __restrict__ lng, const float* __restrict__ lnb,
                    float* __restrict__ out) {
    __shared__ unsigned hsb[32 * 72];     // 9216 B: rows 0-15 b0, 16-31 b1; u32 = cols(2l,2l+1)
    __shared__ float hs[16][VALD + 2];
    __shared__ float ps[16][16];
    __shared__ float psq[16][16];
    __shared__ float mu_s[16], rs_s[16];
    int i0 = blockIdx.x * 16;
    int tid = threadIdx.x;
    int wave = tid >> 6, lane = tid & 63;

    // ---------------- aggregate phase ----------------
    for (int rr = 0; rr < 4; ++rr) {
        int i = i0 + wave * 4 + rr;
        int start = offsets[i], len = offsets[i + 1] - start;
        float acc00 = 0.f, acc01 = 0.f, acc10 = 0.f, acc11 = 0.f;
        if (len > 0) {
            if (len <= 64) {
                float ex0 = 0.f, ex1 = 0.f; int colv = 0;
                if (lane < len) {
                    uint2 e = edge_s[start + lane];
                    colv = (int)e.x;
                    float cv = __uint_as_float(e.y);
                    ex0 = __expf(cv * ksum[colv]);
                    ex1 = __expf(cv * ksum[NNODE + colv]);
                }
                float s0 = ex0, s1 = ex1;
#pragma unroll
                for (int o = 1; o < 64; o <<= 1) { s0 += __shfl_xor(s0, o); s1 += __shfl_xor(s1, o); }
                float inv0 = 1.0f / s0, inv1 = 1.0f / s1;
                int p = 0;
                for (; p + 3 < len; p += 4) {
                    int c0 = __shfl(colv, p),     c1 = __shfl(colv, p + 1);
                    int c2 = __shfl(colv, p + 2), c3 = __shfl(colv, p + 3);
                    float wa0 = __shfl(ex0, p) * inv0,     wb0 = __shfl(ex1, p) * inv1;
                    float wa1 = __shfl(ex0, p + 1) * inv0, wb1 = __shfl(ex1, p + 1) * inv1;
                    float wa2 = __shfl(ex0, p + 2) * inv0, wb2 = __shfl(ex1, p + 2) * inv1;
                    float wa3 = __shfl(ex0, p + 3) * inv0, wb3 = __shfl(ex1, p + 3) * inv1;
                    uint2 v0 = values_pk[(size_t)c0 * 64 + lane];
                    uint2 v1 = values_pk[(size_t)c1 * 64 + lane];
                    uint2 v2 = values_pk[(size_t)c2 * 64 + lane];
                    uint2 v3 = values_pk[(size_t)c3 * 64 + lane];
                    acc00 += wa0 * __uint_as_float(v0.x << 16) + wa1 * __uint_as_float(v1.x << 16)
                           + wa2 * __uint_as_float(v2.x << 16) + wa3 * __uint_as_float(v3.x << 16);
                    acc01 += wa0 * __uint_as_float(v0.x & 0xFFFF0000u) + wa1 * __uint_as_float(v1.x & 0xFFFF0000u)
                           + wa2 * __uint_as_float(v2.x & 0xFFFF0000u) + wa3 * __uint_as_float(v3.x & 0xFFFF0000u);
                    acc10 += wb0 * __uint_as_float(v0.y << 16) + wb1 * __uint_as_float(v1.y << 16)
                           + wb2 * __uint_as_float(v2.y << 16) + wb3 * __uint_as_float(v3.y << 16);
                    acc11 += wb0 * __uint_as_float(v0.y & 0xFFFF0000u) + wb1 * __uint_as_float(v1.y & 0xFFFF0000u)
                           + wb2 * __uint_as_float(v2.y & 0xFFFF0000u) + wb3 * __uint_as_float(v3.y & 0xFFFF0000u);
                }
                for (; p < len; ++p) {
                    int c = __shfl(colv, p);
                    float w0 = __shfl(ex0, p) * inv0;
                    float w1 = __shfl(ex1, p) * inv1;
                    uint2 v = values_pk[(size_t)c * 64 + lane];
                    acc00 += w0 * __uint_as_float(v.x << 16);
                    acc01 += w0 * __uint_as_float(v.x & 0xFFFF0000u);
                    acc10 += w1 * __uint_as_float(v.y << 16);
                    acc11 += w1 * __uint_as_float(v.y & 0xFFFF0000u);
                }
            } else {
                float s0 = 0.f, s1 = 0.f;
                for (int basep = 0; basep < len; basep += 64) {
                    int q = basep + lane;
                    if (q < len) {
                        uint2 e = edge_s[start + q];
                        int c = (int)e.x;
                        float cv = __uint_as_float(e.y);
                        s0 += __expf(cv * ksum[c]);
                        s1 += __expf(cv * ksum[NNODE + c]);
                    }
                }
#pragma unroll
                for (int o = 1; o < 64; o <<= 1) { s0 += __shfl_xor(s0, o); s1 += __shfl_xor(s1, o); }
                float inv0 = 1.0f / s0, inv1 = 1.0f / s1;
                for (int p = 0; p < len; ++p) {
                    uint2 e = edge_s[start + p];
                    int c = (int)e.x;
                    float cv = __uint_as_float(e.y);
                    float w0 = __expf(cv * ksum[c]) * inv0;
                    float w1 = __expf(cv * ksum[NNODE + c]) * inv1;
                    uint2 v = values_pk[(size_t)c * 64 + lane];
                    acc00 += w0 * __uint_as_float(v.x << 16);
                    acc01 += w0 * __uint_as_float(v.x & 0xFFFF0000u);
                    acc10 += w1 * __uint_as_float(v.y << 16);
                    acc11 += w1 * __uint_as_float(v.y & 0xFFFF0000u);
                }
            }
        }
        int row0 = wave * 4 + rr;   // node-local 0..15
        hsb[row0 * 72 + lane]        = (unsigned)f2bf(acc00) | ((unsigned)f2bf(acc01) << 16);
        hsb[(16 + row0) * 72 + lane] = (unsigned)f2bf(acc10) | ((unsigned)f2bf(acc11) << 16);
    }
    __syncthreads();

    // ---------------- out phase: 2 tiles (batch0 rows, batch1 rows) ----------------
    int m = lane & 15, quad = lane >> 4;
    int n0 = wave * 32;
    for (int tb = 0; tb < 2; ++tb) {
        f32x4 a0 = {0.f, 0.f, 0.f, 0.f}, a1 = {0.f, 0.f, 0.f, 0.f};
        const unsigned* arow = hsb + (tb * 16 + m) * 72;
#pragma unroll
        for (int kk = 0; kk < 4; ++kk) {
            int k0 = kk * 32 + quad * 8;
            bf16x8 af = *(const bf16x8*)(arow + (k0 >> 1));
            bf16x8 b0 = *(const bf16x8*)(owT + (size_t)(n0 + m) * VALD + k0);
            bf16x8 b1 = *(const bf16x8*)(owT + (size_t)(n0 + 16 + m) * VALD + k0);
            a0 = __builtin_amdgcn_mfma_f32_16x16x32_bf16(af, b0, a0, 0, 0, 0);
            a1 = __builtin_amdgcn_mfma_f32_16x16x32_bf16(af, b1, a1, 0, 0, 0);
        }
#pragma unroll
        for (int r = 0; r < 4; ++r) {
            int row = quad * 4 + r;
            {
                int col = n0 + m;
                float h = a0[r] + ob[col];
                hs[row][col] = h / (1.f + __expf(-h));
            }
            {
                int col = n0 + 16 + m;
                float h = a1[r] + ob[col];
                hs[row][col] = h / (1.f + __expf(-h));
            }
        }
        __syncthreads();
        {
            int row = tid >> 4, seg = tid & 15;
            float s = 0.f, q = 0.f;
#pragma unroll
            for (int j = 0; j < 8; ++j) {
                float v = hs[row][seg * 8 + j];
                s += v; q += v * v;
            }
            ps[row][seg] = s; psq[row][seg] = q;
        }
        __syncthreads();
        if (tid < 16) {
            float s = 0.f, q = 0.f;
#pragma unroll
            for (int j = 0; j < 16; ++j) { s += ps[tid][j]; q += psq[tid][j]; }
            float mu = s * (1.f / 128.f);
            float var = q * (1.f / 128.f) - mu * mu;
            mu_s[tid] = mu;
            rs_s[tid] = rsqrtf(var + 1e-5f);
        }
        __syncthreads();
        size_t obase = (size_t)(tb * NNODE + i0) * VALD;
#pragma unroll
        for (int j = 0; j < 8; ++j) {
            int e = tid + 256 * j;
            int row = e >> 7, col = e & 127;
            out[obase + (size_t)row * VALD + col] =
                (hs[row][col] - mu_s[row]) * rs_s[row] * lng[col] + lnb[col];
        }
        __syncthreads();   // hs/ps reuse for tile 1
    }
}

// ---------------------------------------------------------------------------
extern "C" void kernel_launch(void* const* d_in, const int* in_sizes, int n_in,
                              void* d_out, int out_size, void* d_ws, size_t ws_size,
                              hipStream_t stream) {
    (void)in_sizes; (void)n_in; (void)out_size; (void)ws_size;
    const float* x    = (const float*)d_in[0];
    const float* conn = (const float*)d_in[1];
    const float* kw   = (const float*)d_in[2];
    const float* kb   = (const float*)d_in[3];
    const float* vw   = (const float*)d_in[4];
    const float* vb   = (const float*)d_in[5];
    const float* ow   = (const float*)d_in[6];
    const float* ob   = (const float*)d_in[7];
    const float* lng  = (const float*)d_in[8];
    const float* lnb  = (const float*)d_in[9];
    const int* rows   = (const int*)d_in[10];
    const int* cols   = (const int*)d_in[11];
    float* out        = (float*)d_out;

    char* w = (char*)d_ws;
    auto alloc = [&](size_t bytes) {
        char* p = w;
        w += (bytes + 255) & ~(size_t)255;
        return p;
    };
    uint2* values_pk = (uint2*)alloc((size_t)NNODE * 512);       // 25.6 MB
    float* ksum    = (float*)alloc((size_t)MTOT * 4);
    float* kwsum   = (float*)alloc(256 * 4);
    int*   counts  = (int*)alloc((size_t)NNODE * 4);
    int*   cursor  = (int*)alloc((size_t)NNODE * 4);
    int*   offsets = (int*)alloc((size_t)(NNODE + 1) * 4);
    int*   psum    = (int*)alloc((size_t)NCHUNK * 4);
    int*   flags   = (int*)alloc(2 * 4);
    uint2* edge_s  = (uint2*)alloc((size_t)NEDGE * 8);           // 6.4 MB
    unsigned short* vwT = (unsigned short*)alloc((size_t)INPD * VALD * 2);
    unsigned short* owT = (unsigned short*)alloc((size_t)VALD * VALD * 2);

    prep_kernel<<<129 + 196, 256, 0, stream>>>(kw, kb, vw, ow, kwsum, vwT, owT, counts, flags);
    values_build_kernel<<<VBLK + (NEDGE + 511) / 512, 512, 0, stream>>>(
        x, vb, kwsum, vwT, rows, values_pk, ksum, counts);
    scan_scatter_kernel<<<NCHUNK, 256, 0, stream>>>(
        counts, psum, flags, offsets, cursor, rows, cols, conn, edge_s);
    agg_out_kernel<<<VBLK, 256, 0, stream>>>(
        offsets, edge_s, ksum, values_pk, owT, ob, lng, lnb, out);
}

// Round 6
// 326.254 us; speedup vs baseline: 1.0254x; 1.0254x over previous
//
#include <hip/hip_runtime.h>
#include <hip/hip_bf16.h>

// BatchedSemiAttention: B=2, N=50000, E=800000, INP=128, KEY=64, VAL=128
#define NB    2
#define NNODE 50000
#define NEDGE 800000
#define INPD  128
#define KEYD  64
#define VALD  128
#define MTOT  (NB * NNODE)   // 100000 flattened (b,n) rows
#define VBLK  3125           // NNODE/16 blocks for the values GEMM part
#define CHUNK 512
#define NCHUNK ((NNODE + CHUNK - 1) / CHUNK)   // 98
#define EPB   ((NEDGE + NCHUNK - 1) / NCHUNK)  // edges per scan_scatter block

typedef __attribute__((ext_vector_type(8))) short bf16x8;
typedef __attribute__((ext_vector_type(4))) float f32x4;

__device__ __forceinline__ unsigned short f2bf(float f) {
    unsigned u = __float_as_uint(f);
    u += 0x7FFFu + ((u >> 16) & 1u);   // RNE
    return (unsigned short)(u >> 16);
}

__device__ __forceinline__ float rl_f(float v, int l) {   // wave-uniform lane read
    return __uint_as_float((unsigned)__builtin_amdgcn_readlane((int)__float_as_uint(v), l));
}

// ---------------------------------------------------------------------------
// Prep: bf16 transposes of v_w / out_w into [n][k]; kwsum (col-sums of k_w,
// +kb sum at [128]); zero CSR counts + sync flags. One launch.
// ---------------------------------------------------------------------------
__global__ void prep_kernel(const float* __restrict__ kw, const float* __restrict__ kb,
                            const float* __restrict__ vw, const float* __restrict__ ow,
                            float* __restrict__ kwsum,
                            unsigned short* __restrict__ vwT, unsigned short* __restrict__ owT,
                            int* __restrict__ counts, int* __restrict__ flags) {
    int bid = blockIdx.x, tid = threadIdx.x;
    if (bid < 64) {
        int idx = bid * 256 + tid;            // [0,16384)
        int n = idx >> 7, k = idx & 127;
        vwT[idx] = f2bf(vw[k * VALD + n]);
    } else if (bid < 128) {
        int idx = (bid - 64) * 256 + tid;
        int n = idx >> 7, k = idx & 127;
        owT[idx] = f2bf(ow[k * VALD + n]);
    } else if (bid == 128) {
        if (tid < INPD) {
            float s = 0.f;
            for (int j = 0; j < KEYD; ++j) s += kw[tid * KEYD + j];
            kwsum[tid] = s;
        }
        if (tid == 129) {
            float s = 0.f;
            for (int j = 0; j < KEYD; ++j) s += kb[j];
            kwsum[INPD] = s;                  // kbsum
        }
        if (tid == 200) flags[0] = 0;
        if (tid == 201) flags[1] = 0;
    } else {
        int idx = (bid - 129) * 256 + tid;
        if (idx < NNODE) counts[idx] = 0;
    }
}

// ---------------------------------------------------------------------------
// Fused values GEMM (both batches, 16 nodes/block) + ksum + edge histogram.
//   xsb  [32][136] bf16 - x tile converted ONCE during staging (rows 0-15 b0,
//                         16-31 b1; stride 272 B keeps 16B-aligned b128 reads,
//                         <=2-way bank aliasing = free)
//   pk32 [16][132] u32  - packed (b0|b1<<16) output tile, repacked on flush.
// ksum_pk[node] = float2{b0,b1} -> one 8B gather in the softmax phase.
// values_pk layout per node: 64 x uint2 { b0 cols(2l,2l+1), b1 cols(2l,2l+1) }
// ---------------------------------------------------------------------------
__global__ __launch_bounds__(512)
void values_build_kernel(const float* __restrict__ x, const float* __restrict__ vb,
                         const float* __restrict__ kwsum,
                         const unsigned short* __restrict__ vwT,
                         const int* __restrict__ rows_e,
                         uint2* __restrict__ values_pk, float2* __restrict__ ksum_pk,
                         int* __restrict__ counts) {
    __shared__ unsigned short xsb[32 * 136];  // 8704 B
    __shared__ unsigned pk32[16 * 132];       // 8448 B
    if (blockIdx.x >= VBLK) {
        // histogram part, overlapped with the GEMM blocks
        int e = (blockIdx.x - VBLK) * 512 + threadIdx.x;
        if (e < NEDGE) atomicAdd(&counts[rows_e[e]], 1);
        return;
    }
    int node0 = blockIdx.x * 16;
    int tid = threadIdx.x;
    // Staging: coalesced float4 per thread per batch; convert to bf16 ONCE;
    // fp32 ksum partial computed here (exact path feeding exp).
    {
        int row = tid >> 5;            // 0..15
        int cg  = (tid & 31) * 4;      // col 0..124
        float4 v0 = ((const float4*)(x + (size_t)node0 * INPD))[tid];
        float4 v1 = ((const float4*)(x + (size_t)(NNODE + node0) * INPD))[tid];
        float4 kc = *(const float4*)(kwsum + cg);
        float s0 = v0.x * kc.x + v0.y * kc.y + v0.z * kc.z + v0.w * kc.w;
        float s1 = v1.x * kc.x + v1.y * kc.y + v1.z * kc.z + v1.w * kc.w;
        uint2 p0, p1;
        p0.x = (unsigned)f2bf(v0.x) | ((unsigned)f2bf(v0.y) << 16);
        p0.y = (unsigned)f2bf(v0.z) | ((unsigned)f2bf(v0.w) << 16);
        p1.x = (unsigned)f2bf(v1.x) | ((unsigned)f2bf(v1.y) << 16);
        p1.y = (unsigned)f2bf(v1.z) | ((unsigned)f2bf(v1.w) << 16);
        *(uint2*)(xsb + row * 136 + cg) = p0;
        *(uint2*)(xsb + (16 + row) * 136 + cg) = p1;
#pragma unroll
        for (int o = 16; o >= 1; o >>= 1) { s0 += __shfl_xor(s0, o); s1 += __shfl_xor(s1, o); }
        if ((tid & 31) == 0) {
            float kb = kwsum[INPD];
            ksum_pk[node0 + row] = make_float2(s0 + kb, s1 + kb);
        }
    }
    __syncthreads();

    int wave = tid >> 6, lane = tid & 63;
    int m = lane & 15, quad = lane >> 4;
    int n0 = wave * 16;
    f32x4 acc0 = {0.f, 0.f, 0.f, 0.f};   // batch 0
    f32x4 acc1 = {0.f, 0.f, 0.f, 0.f};   // batch 1
    const unsigned short* arow0 = xsb + m * 136;
    const unsigned short* arow1 = xsb + (16 + m) * 136;
    const unsigned short* brow  = vwT + (size_t)(n0 + m) * INPD;
#pragma unroll
    for (int kk = 0; kk < 4; ++kk) {
        int k0 = kk * 32 + quad * 8;
        bf16x8 a0 = *(const bf16x8*)(arow0 + k0);
        bf16x8 a1 = *(const bf16x8*)(arow1 + k0);
        bf16x8 bfrag = *(const bf16x8*)(brow + k0);
        acc0 = __builtin_amdgcn_mfma_f32_16x16x32_bf16(a0, bfrag, acc0, 0, 0, 0);
        acc1 = __builtin_amdgcn_mfma_f32_16x16x32_bf16(a1, bfrag, acc1, 0, 0, 0);
    }
    int col = n0 + m;
    float vbc = vb[col];
#pragma unroll
    for (int r = 0; r < 4; ++r) {
        int nl = quad * 4 + r;                  // node_local
        pk32[nl * 132 + col] = (unsigned)f2bf(acc0[r] + vbc)
                             | ((unsigned)f2bf(acc1[r] + vbc) << 16);
    }
    __syncthreads();
    // Repack + coalesced flush: thread t -> node t>>5, col-group t&31 (4 cols).
    {
        int nl = tid >> 5, cg = tid & 31;
        const unsigned* p = pk32 + nl * 132 + cg * 4;
        unsigned p0 = p[0], p1 = p[1], p2 = p[2], p3 = p[3];
        uint4 r;
        r.x = (p0 & 0xFFFFu) | (p1 << 16);                 // b0 cols 4cg,4cg+1
        r.y = (p0 >> 16) | (p1 & 0xFFFF0000u);             // b1 cols 4cg,4cg+1
        r.z = (p2 & 0xFFFFu) | (p3 << 16);                 // b0 cols 4cg+2,4cg+3
        r.w = (p2 >> 16) | (p3 & 0xFFFF0000u);             // b1 cols 4cg+2,4cg+3
        *(uint4*)((char*)values_pk + (size_t)(node0 + nl) * 512 + cg * 16) = r;
    }
}

// ---------------------------------------------------------------------------
// Fused scan1+scan2+scan3+scatter: 98 blocks (always co-resident on 256 CUs),
// device-scope atomics for the two global barriers.
// ---------------------------------------------------------------------------
__global__ __launch_bounds__(256)
void scan_scatter_kernel(const int* __restrict__ counts,
                         int* __restrict__ psum, int* __restrict__ flags,
                         int* __restrict__ offsets, int* __restrict__ cursor,
                         const int* __restrict__ rows, const int* __restrict__ cols,
                         const float* __restrict__ conn,
                         uint2* __restrict__ edge_s) {
    __shared__ int wt0[4], wt1[4];
    __shared__ int pshared[128];
    __shared__ int base_sh;
    int b = blockIdx.x, t = threadIdx.x;
    int lane = t & 63, wv = t >> 6;
    int i0 = b * CHUNK + t, i1 = i0 + 256;
    int v0 = (i0 < NNODE) ? counts[i0] : 0;
    int v1 = (i1 < NNODE) ? counts[i1] : 0;
    // ---- phase 1: publish this chunk's sum
    {
        int v = v0 + v1;
#pragma unroll
        for (int o = 1; o < 64; o <<= 1) v += __shfl_xor(v, o);
        if (lane == 0) wt0[wv] = v;
        __syncthreads();
        if (t == 0) {
            int s = wt0[0] + wt0[1] + wt0[2] + wt0[3];
            __hip_atomic_store(&psum[b], s, __ATOMIC_RELEASE, __HIP_MEMORY_SCOPE_AGENT);
            __hip_atomic_fetch_add(&flags[0], 1, __ATOMIC_ACQ_REL, __HIP_MEMORY_SCOPE_AGENT);
            while (__hip_atomic_load(&flags[0], __ATOMIC_ACQUIRE, __HIP_MEMORY_SCOPE_AGENT) < NCHUNK) {}
        }
        __syncthreads();
    }
    // ---- phase 2: chunk base + within-chunk exclusive scan -> offsets/cursor
    if (t < 128)
        pshared[t] = (t < NCHUNK)
            ? __hip_atomic_load(&psum[t], __ATOMIC_RELAXED, __HIP_MEMORY_SCOPE_AGENT) : 0;
    __syncthreads();
    if (t == 0) {
        int s = 0;
        for (int j = 0; j < b; ++j) s += pshared[j];
        base_sh = s;
        if (b == 0) {
            int tot = 0;
            for (int j = 0; j < NCHUNK; ++j) tot += pshared[j];
            offsets[NNODE] = tot;
        }
    }
    __syncthreads();
    {
        int x0 = v0, x1 = v1;
#pragma unroll
        for (int o = 1; o < 64; o <<= 1) { int y = __shfl_up(x0, o); if (lane >= o) x0 += y; }
#pragma unroll
        for (int o = 1; o < 64; o <<= 1) { int y = __shfl_up(x1, o); if (lane >= o) x1 += y; }
        if (lane == 63) { wt0[wv] = x0; wt1[wv] = x1; }
        __syncthreads();
        int base = base_sh;
        int acc0 = base;
        for (int j = 0; j < wv; ++j) acc0 += wt0[j];
        int excl0 = acc0 + x0 - v0;
        int acc1 = base + wt0[0] + wt0[1] + wt0[2] + wt0[3];
        for (int j = 0; j < wv; ++j) acc1 += wt1[j];
        int excl1 = acc1 + x1 - v1;
        if (i0 < NNODE) {
            offsets[i0] = excl0;
            __hip_atomic_store(&cursor[i0], excl0, __ATOMIC_RELAXED, __HIP_MEMORY_SCOPE_AGENT);
        }
        if (i1 < NNODE) {
            offsets[i1] = excl1;
            __hip_atomic_store(&cursor[i1], excl1, __ATOMIC_RELAXED, __HIP_MEMORY_SCOPE_AGENT);
        }
    }
    // ---- barrier 2: all cursors ready
    __syncthreads();
    if (t == 0) {
        __hip_atomic_fetch_add(&flags[1], 1, __ATOMIC_ACQ_REL, __HIP_MEMORY_SCOPE_AGENT);
        while (__hip_atomic_load(&flags[1], __ATOMIC_ACQUIRE, __HIP_MEMORY_SCOPE_AGENT) < NCHUNK) {}
    }
    __syncthreads();
    // ---- phase 3: scatter this block's edge slice
    int e0 = b * EPB;
    int e1 = min(e0 + EPB, NEDGE);
    for (int e = e0 + t; e < e1; e += 256) {
        int r = rows[e];
        int o = atomicAdd(&cursor[r], 1);
        edge_s[o] = make_uint2((unsigned)cols[e], __float_as_uint(conn[e]));
    }
}

// ---------------------------------------------------------------------------
// Fused aggregate + output GEMM + silu + LayerNorm. Block owns 16 consecutive
// nodes. Gather loop uses v_readlane (wave-uniform p) instead of bpermute,
// pre-normalized weights, and scalar gather base (SGPR + lane offset).
// ---------------------------------------------------------------------------
__global__ __launch_bounds__(256)
void agg_out_kernel(const int* __restrict__ offsets,
                    const uint2* __restrict__ edge_s,
                    const float2* __restrict__ ksum_pk,
                    const uint2* __restrict__ values_pk,
                    const unsigned short* __restrict__ owT,
                    const float* __restrict__ ob,
                    const float* __restrict__ lng, const float* __restrict__ lnb,
                    float* __restrict__ out) {
    __shared__ unsigned hsb[32 * 72];     // 9216 B: rows 0-15 b0, 16-31 b1
    __shared__ float hs[16][VALD + 2];
    __shared__ float ps[16][16];
    __shared__ float psq[16][16];
    __shared__ float mu_s[16], rs_s[16];
    int i0 = blockIdx.x * 16;
    int tid = threadIdx.x;
    int wave = tid >> 6, lane = tid & 63;

    // ---------------- aggregate phase ----------------
    for (int rr = 0; rr < 4; ++rr) {
        int i = i0 + wave * 4 + rr;
        int start = __builtin_amdgcn_readfirstlane(offsets[i]);
        int len   = __builtin_amdgcn_readfirstlane(offsets[i + 1]) - start;
        float acc00 = 0.f, acc01 = 0.f, acc10 = 0.f, acc11 = 0.f;
        if (len > 0) {
            if (len <= 64) {
                float ex0 = 0.f, ex1 = 0.f; int colv = 0;
                if (lane < len) {
                    uint2 e = edge_s[start + lane];
                    colv = (int)e.x;
                    float cv = __uint_as_float(e.y);
                    float2 ks = ksum_pk[colv];
                    ex0 = __expf(cv * ks.x);
                    ex1 = __expf(cv * ks.y);
                }
                float s0 = ex0, s1 = ex1;
#pragma unroll
                for (int o = 1; o < 64; o <<= 1) { s0 += __shfl_xor(s0, o); s1 += __shfl_xor(s1, o); }
                ex0 *= 1.0f / s0;            // pre-normalized weights
                ex1 *= 1.0f / s1;
                int p = 0;
                for (; p + 4 <= len; p += 4) {
                    int c0 = __builtin_amdgcn_readlane(colv, p);
                    int c1 = __builtin_amdgcn_readlane(colv, p + 1);
                    int c2 = __builtin_amdgcn_readlane(colv, p + 2);
                    int c3 = __builtin_amdgcn_readlane(colv, p + 3);
                    float wa0 = rl_f(ex0, p),     wb0 = rl_f(ex1, p);
                    float wa1 = rl_f(ex0, p + 1), wb1 = rl_f(ex1, p + 1);
                    float wa2 = rl_f(ex0, p + 2), wb2 = rl_f(ex1, p + 2);
                    float wa3 = rl_f(ex0, p + 3), wb3 = rl_f(ex1, p + 3);
                    uint2 v0 = values_pk[(size_t)c0 * 64 + lane];
                    uint2 v1 = values_pk[(size_t)c1 * 64 + lane];
                    uint2 v2 = values_pk[(size_t)c2 * 64 + lane];
                    uint2 v3 = values_pk[(size_t)c3 * 64 + lane];
                    acc00 += wa0 * __uint_as_float(v0.x << 16) + wa1 * __uint_as_float(v1.x << 16)
                           + wa2 * __uint_as_float(v2.x << 16) + wa3 * __uint_as_float(v3.x << 16);
                    acc01 += wa0 * __uint_as_float(v0.x & 0xFFFF0000u) + wa1 * __uint_as_float(v1.x & 0xFFFF0000u)
                           + wa2 * __uint_as_float(v2.x & 0xFFFF0000u) + wa3 * __uint_as_float(v3.x & 0xFFFF0000u);
                    acc10 += wb0 * __uint_as_float(v0.y << 16) + wb1 * __uint_as_float(v1.y << 16)
                           + wb2 * __uint_as_float(v2.y << 16) + wb3 * __uint_as_float(v3.y << 16);
                    acc11 += wb0 * __uint_as_float(v0.y & 0xFFFF0000u) + wb1 * __uint_as_float(v1.y & 0xFFFF0000u)
                           + wb2 * __uint_as_float(v2.y & 0xFFFF0000u) + wb3 * __uint_as_float(v3.y & 0xFFFF0000u);
                }
                for (; p < len; ++p) {
                    int c = __builtin_amdgcn_readlane(colv, p);
                    float w0 = rl_f(ex0, p), w1 = rl_f(ex1, p);
                    uint2 v = values_pk[(size_t)c * 64 + lane];
                    acc00 += w0 * __uint_as_float(v.x << 16);
                    acc01 += w0 * __uint_as_float(v.x & 0xFFFF0000u);
                    acc10 += w1 * __uint_as_float(v.y << 16);
                    acc11 += w1 * __uint_as_float(v.y & 0xFFFF0000u);
                }
            } else {
                float s0 = 0.f, s1 = 0.f;
                for (int basep = 0; basep < len; basep += 64) {
                    int q = basep + lane;
                    if (q < len) {
                        uint2 e = edge_s[start + q];
                        float cv = __uint_as_float(e.y);
                        float2 ks = ksum_pk[(int)e.x];
                        s0 += __expf(cv * ks.x);
                        s1 += __expf(cv * ks.y);
                    }
                }
#pragma unroll
                for (int o = 1; o < 64; o <<= 1) { s0 += __shfl_xor(s0, o); s1 += __shfl_xor(s1, o); }
                float inv0 = 1.0f / s0, inv1 = 1.0f / s1;
                for (int p = 0; p < len; ++p) {
                    uint2 e = edge_s[start + p];
                    int c = (int)e.x;
                    float cv = __uint_as_float(e.y);
                    float2 ks = ksum_pk[c];
                    float w0 = __expf(cv * ks.x) * inv0;
                    float w1 = __expf(cv * ks.y) * inv1;
                    uint2 v = values_pk[(size_t)c * 64 + lane];
                    acc00 += w0 * __uint_as_float(v.x << 16);
                    acc01 += w0 * __uint_as_float(v.x & 0xFFFF0000u);
                    acc10 += w1 * __uint_as_float(v.y << 16);
                    acc11 += w1 * __uint_as_float(v.y & 0xFFFF0000u);
                }
            }
        }
        int row0 = wave * 4 + rr;   // node-local 0..15
        hsb[row0 * 72 + lane]        = (unsigned)f2bf(acc00) | ((unsigned)f2bf(acc01) << 16);
        hsb[(16 + row0) * 72 + lane] = (unsigned)f2bf(acc10) | ((unsigned)f2bf(acc11) << 16);
    }
    __syncthreads();

    // ---------------- out phase: 2 tiles (batch0 rows, batch1 rows) ----------------
    int m = lane & 15, quad = lane >> 4;
    int n0 = wave * 32;
    for (int tb = 0; tb < 2; ++tb) {
        f32x4 a0 = {0.f, 0.f, 0.f, 0.f}, a1 = {0.f, 0.f, 0.f, 0.f};
        const unsigned* arow = hsb + (tb * 16 + m) * 72;
#pragma unroll
        for (int kk = 0; kk < 4; ++kk) {
            int k0 = kk * 32 + quad * 8;
            bf16x8 af = *(const bf16x8*)(arow + (k0 >> 1));
            bf16x8 b0 = *(const bf16x8*)(owT + (size_t)(n0 + m) * VALD + k0);
            bf16x8 b1 = *(const bf16x8*)(owT + (size_t)(n0 + 16 + m) * VALD + k0);
            a0 = __builtin_amdgcn_mfma_f32_16x16x32_bf16(af, b0, a0, 0, 0, 0);
            a1 = __builtin_amdgcn_mfma_f32_16x16x32_bf16(af, b1, a1, 0, 0, 0);
        }
#pragma unroll
        for (int r = 0; r < 4; ++r) {
            int row = quad * 4 + r;
            {
                int col = n0 + m;
                float h = a0[r] + ob[col];
                hs[row][col] = h / (1.f + __expf(-h));
            }
            {
                int col = n0 + 16 + m;
                float h = a1[r] + ob[col];
                hs[row][col] = h / (1.f + __expf(-h));
            }
        }
        __syncthreads();
        {
            int row = tid >> 4, seg = tid & 15;
            float s = 0.f, q = 0.f;
#pragma unroll
            for (int j = 0; j < 8; ++j) {
                float v = hs[row][seg * 8 + j];
                s += v; q += v * v;
            }
            ps[row][seg] = s; psq[row][seg] = q;
        }
        __syncthreads();
        if (tid < 16) {
            float s = 0.f, q = 0.f;
#pragma unroll
            for (int j = 0; j < 16; ++j) { s += ps[tid][j]; q += psq[tid][j]; }
            float mu = s * (1.f / 128.f);
            float var = q * (1.f / 128.f) - mu * mu;
            mu_s[tid] = mu;
            rs_s[tid] = rsqrtf(var + 1e-5f);
        }
        __syncthreads();
        size_t obase = (size_t)(tb * NNODE + i0) * VALD;
#pragma unroll
        for (int j = 0; j < 8; ++j) {
            int e = tid + 256 * j;
            int row = e >> 7, col = e & 127;
            out[obase + (size_t)row * VALD + col] =
                (hs[row][col] - mu_s[row]) * rs_s[row] * lng[col] + lnb[col];
        }
        __syncthreads();   // hs/ps reuse for tile 1
    }
}

// ---------------------------------------------------------------------------
extern "C" void kernel_launch(void* const* d_in, const int* in_sizes, int n_in,
                              void* d_out, int out_size, void* d_ws, size_t ws_size,
                              hipStream_t stream) {
    (void)in_sizes; (void)n_in; (void)out_size; (void)ws_size;
    const float* x    = (const float*)d_in[0];
    const float* conn = (const float*)d_in[1];
    const float* kw   = (const float*)d_in[2];
    const float* kb   = (const float*)d_in[3];
    const float* vw   = (const float*)d_in[4];
    const float* vb   = (const float*)d_in[5];
    const float* ow   = (const float*)d_in[6];
    const float* ob   = (const float*)d_in[7];
    const float* lng  = (const float*)d_in[8];
    const float* lnb  = (const float*)d_in[9];
    const int* rows   = (const int*)d_in[10];
    const int* cols   = (const int*)d_in[11];
    float* out        = (float*)d_out;

    char* w = (char*)d_ws;
    auto alloc = [&](size_t bytes) {
        char* p = w;
        w += (bytes + 255) & ~(size_t)255;
        return p;
    };
    uint2* values_pk = (uint2*)alloc((size_t)NNODE * 512);       // 25.6 MB
    float2* ksum_pk  = (float2*)alloc((size_t)NNODE * 8);
    float* kwsum   = (float*)alloc(256 * 4);
    int*   counts  = (int*)alloc((size_t)NNODE * 4);
    int*   cursor  = (int*)alloc((size_t)NNODE * 4);
    int*   offsets = (int*)alloc((size_t)(NNODE + 1) * 4);
    int*   psum    = (int*)alloc((size_t)NCHUNK * 4);
    int*   flags   = (int*)alloc(2 * 4);
    uint2* edge_s  = (uint2*)alloc((size_t)NEDGE * 8);           // 6.4 MB
    unsigned short* vwT = (unsigned short*)alloc((size_t)INPD * VALD * 2);
    unsigned short* owT = (unsigned short*)alloc((size_t)VALD * VALD * 2);

    prep_kernel<<<129 + 196, 256, 0, stream>>>(kw, kb, vw, ow, kwsum, vwT, owT, counts, flags);
    values_build_kernel<<<VBLK + (NEDGE + 511) / 512, 512, 0, stream>>>(
        x, vb, kwsum, vwT, rows, values_pk, ksum_pk, counts);
    scan_scatter_kernel<<<NCHUNK, 256, 0, stream>>>(
        counts, psum, flags, offsets, cursor, rows, cols, conn, edge_s);
    agg_out_kernel<<<VBLK, 256, 0, stream>>>(
        offsets, edge_s, ksum_pk, values_pk, owT, ob, lng, lnb, out);
}